// Round 1
// 440.731 us; speedup vs baseline: 1.2083x; 1.2083x over previous
//
#include <hip/hip_runtime.h>

// Problem constants (fixed by the reference: B=4, S=2048, D_IN=D_OUT=4096)
#define GM 8192
#define GN 4096
#define GK 4096
#define NT (GK / 64)

// Workspace layout (bytes)
#define QX_OFF   0ull                      // int8 [8192][4096] = 33.5 MB; first 24 KB
                                           // doubles as minmax partials (consumed by
                                           // k_params BEFORE k_quant overwrites it)
#define QW_OFF   33554432ull               // int8 [4096][4096]  = 16.8 MB
#define RSX_OFF  50331648ull               // int32[8192]
#define RSW_OFF  50364416ull               // int32[4096]
#define PRM_OFF  50380832ull               // params: sx, zxf, sw, zwf, sxsw, zxi, zwi

#define MMB_X 2048                         // minmax blocks for x
#define MMB_W 1024                         // minmax blocks for W

using v4i  = __attribute__((ext_vector_type(4)))  int;
using v16i = __attribute__((ext_vector_type(16))) int;

// ---------- helpers ----------
__device__ __forceinline__ unsigned encf(float x) {
    unsigned u = __float_as_uint(x);
    return (u & 0x80000000u) ? ~u : (u | 0x80000000u);
}
__device__ __forceinline__ float decf(unsigned e) {
    unsigned u = (e & 0x80000000u) ? (e & 0x7FFFFFFFu) : ~e;
    return __uint_as_float(u);
}

__device__ __forceinline__ void async16(const signed char* g, signed char* l) {
    // 16B per lane, LDS dest = wave-uniform base + lane*16 (m104/m108 rule)
    __builtin_amdgcn_global_load_lds((const __attribute__((address_space(1))) void*)g,
                                     (__attribute__((address_space(3))) void*)l,
                                     16, 0, 0);
}

// ---------- kernels ----------
// Per-block partial max / max(-x) written with PLAIN STORES (no atomics: 12K
// same-address device-scope atomicMax serialize at the coherence point).
// Layout in part[]: [0,2048) mx_x | [2048,4096) nm_x | [4096,5120) mx_w | [5120,6144) nm_w
__global__ void k_minmax(const float4* __restrict__ x, const float4* __restrict__ Wt,
                         unsigned* __restrict__ part) {
    const float4* p; int n4, b0, nb; unsigned* dst;
    if (blockIdx.x < MMB_X) { p = x;  n4 = GM * GK / 4; b0 = blockIdx.x;         nb = MMB_X; dst = part;        }
    else                    { p = Wt; n4 = GN * GK / 4; b0 = blockIdx.x - MMB_X; nb = MMB_W; dst = part + 4096; }
    unsigned mx = 0u, nm = 0u;  // encoded max(x), encoded max(-x)
    for (int i = b0 * 256 + threadIdx.x; i < n4; i += nb * 256) {
        float4 v = p[i];
        mx = max(mx, encf(v.x)); nm = max(nm, encf(-v.x));
        mx = max(mx, encf(v.y)); nm = max(nm, encf(-v.y));
        mx = max(mx, encf(v.z)); nm = max(nm, encf(-v.z));
        mx = max(mx, encf(v.w)); nm = max(nm, encf(-v.w));
    }
    #pragma unroll
    for (int o = 32; o > 0; o >>= 1) {
        mx = max(mx, (unsigned)__shfl_down((int)mx, o));
        nm = max(nm, (unsigned)__shfl_down((int)nm, o));
    }
    __shared__ unsigned smx[4], snm[4];
    int w = threadIdx.x >> 6;
    if ((threadIdx.x & 63) == 0) { smx[w] = mx; snm[w] = nm; }
    __syncthreads();
    if (threadIdx.x == 0) {
        #pragma unroll
        for (int i = 1; i < 4; i++) { mx = max(mx, smx[i]); nm = max(nm, snm[i]); }
        dst[b0]      = mx;   // plain store, no contention
        dst[nb + b0] = nm;
    }
}

// Reduce the 6144 partials (24 KB, L2-hot) and emit quant params. One block.
__global__ void k_params(const unsigned* __restrict__ part, float* prm) {
    const int t = threadIdx.x;
    unsigned v0 = 0u, v1 = 0u, v2 = 0u, v3 = 0u;
    for (int i = t; i < MMB_X; i += 256) {
        v0 = max(v0, part[i]);
        v1 = max(v1, part[MMB_X + i]);
    }
    for (int i = t; i < MMB_W; i += 256) {
        v2 = max(v2, part[4096 + i]);
        v3 = max(v3, part[5120 + i]);
    }
    #pragma unroll
    for (int o = 32; o > 0; o >>= 1) {
        v0 = max(v0, (unsigned)__shfl_down((int)v0, o));
        v1 = max(v1, (unsigned)__shfl_down((int)v1, o));
        v2 = max(v2, (unsigned)__shfl_down((int)v2, o));
        v3 = max(v3, (unsigned)__shfl_down((int)v3, o));
    }
    __shared__ unsigned s[4][4];
    const int wv = t >> 6;
    if ((t & 63) == 0) { s[wv][0] = v0; s[wv][1] = v1; s[wv][2] = v2; s[wv][3] = v3; }
    __syncthreads();
    if (t == 0) {
        #pragma unroll
        for (int i = 1; i < 4; i++) {
            v0 = max(v0, s[i][0]); v1 = max(v1, s[i][1]);
            v2 = max(v2, s[i][2]); v3 = max(v3, s[i][3]);
        }
        float mxx = decf(v0), mnx = -decf(v1);
        float sx  = (mxx - mnx) / 255.0f;
        float zxf = rintf(-128.0f - mnx / sx);
        float mxw = decf(v2), mnw = -decf(v3);
        float sw  = (mxw - mnw) / 255.0f;
        float zwf = rintf(-128.0f - mnw / sw);
        prm[0] = sx; prm[1] = zxf; prm[2] = sw; prm[3] = zwf; prm[4] = sx * sw;
        int* ip = (int*)prm;
        ip[5] = (int)zxf; ip[6] = (int)zwf;
    }
}

// One block (256 threads) per row of 4096 floats; quantize + row sum.
// blocks [0,GM) -> x rows; [GM, GM+GN) -> W rows.
__global__ void k_quant(const float* __restrict__ x, const float* __restrict__ Wt,
                        signed char* __restrict__ qx, signed char* __restrict__ qw,
                        int* __restrict__ rsx, int* __restrict__ rsw,
                        const float* __restrict__ prm) {
    const float* src; signed char* q; int* rs; int pidx, row;
    if (blockIdx.x < GM) { row = blockIdx.x;      src = x;  q = qx; rs = rsx; pidx = 0; }
    else                 { row = blockIdx.x - GM; src = Wt; q = qw; rs = rsw; pidx = 2; }
    const int t = threadIdx.x;
    const float s  = prm[pidx];
    const float zp = prm[pidx + 1];
    const float4* srow = (const float4*)(src + (size_t)row * GK);
    int* qrow = (int*)(q + (size_t)row * GK);
    int acc = 0;
    #pragma unroll
    for (int i = 0; i < 4; i++) {
        float4 v = srow[i * 256 + t];
        int q0 = (int)fminf(fmaxf(rintf(v.x / s) + zp, -128.0f), 127.0f);
        int q1 = (int)fminf(fmaxf(rintf(v.y / s) + zp, -128.0f), 127.0f);
        int q2 = (int)fminf(fmaxf(rintf(v.z / s) + zp, -128.0f), 127.0f);
        int q3 = (int)fminf(fmaxf(rintf(v.w / s) + zp, -128.0f), 127.0f);
        acc += q0 + q1 + q2 + q3;
        qrow[i * 256 + t] = (q0 & 255) | ((q1 & 255) << 8) | ((q2 & 255) << 16)
                          | ((q3 & 255) << 24);
    }
    #pragma unroll
    for (int o = 32; o > 0; o >>= 1) acc += __shfl_down(acc, o);
    __shared__ int sa[4];
    if ((t & 63) == 0) sa[t >> 6] = acc;
    __syncthreads();
    if (t == 0) rs[row] = sa[0] + sa[1] + sa[2] + sa[3];
}

// 256x256 C-tile per block, BK=64. NEW vs prior round:
//  (1) Conflict-free LDS swizzle: chunk c of row r stored at pos c ^ ((r>>1)&3).
//      Bank-quad start = (r&1)*16 + pos*4, so 8 consecutive rows now cover all
//      8 bank-quads (old r&3 XOR re-used the r&1 bit -> 2-way conflict on every
//      ds_read_b128 phase = the measured 3.8e7 SQ_LDS_BANK_CONFLICT).
//  (2) Counted-vmcnt distance-2 pipeline (T4/m201): 3 LDS buffers, raw
//      s_barrier, s_waitcnt vmcnt(4) in steady state (each wave owns exactly 4
//      global_load_lds per K-step) -> prefetch stays in flight across barriers
//      instead of the __syncthreads vmcnt(0) drain.
__global__ __launch_bounds__(512, 2) void k_gemm(
    const signed char* __restrict__ qx, const signed char* __restrict__ qw,
    const int* __restrict__ rsx, const int* __restrict__ rsw,
    const float* __restrict__ bias, const float* __restrict__ prm,
    float* __restrict__ out) {
    __shared__ __align__(16) signed char lds[3][2][256 * 64];  // 96 KB -> 1 block/CU

    const int tid  = threadIdx.x;
    const int lane = tid & 63;
    const int w    = tid >> 6;          // 0..7
    const int bid  = blockIdx.x;
    const int tm0  = (bid >> 4) * 256;  // 32 M-tiles
    const int tn0  = (bid & 15) * 256;  // 16 N-tiles

    // ---- staging setup: waves 0-3 -> A slab rows [w*64,+64); 4-7 -> B ----
    const int slab = w & 3;
    const int sr   = lane >> 2;                           // row 0..15 within 1KB call
    const int sc   = ((lane & 3) ^ ((lane >> 3) & 3)) * 16;  // inverse-swizzled source chunk
    const signed char* gsrc = (w < 4)
        ? qx + (size_t)(tm0 + slab * 64 + sr) * GK + sc
        : qw + (size_t)(tn0 + slab * 64 + sr) * GK + sc;
    const int ldsTensor = (w < 4) ? 0 : 1;
    const int ldsSlab   = slab * 64 * 64;                 // byte offset of 64-row slab

    // ---- fragment / MFMA setup ----
    const int wr = w >> 2;              // 0..1 : wave row (M) position
    const int wc = w & 3;               // 0..3 : wave col (N) position
    const int fr = lane & 31;           // row within 32-block
    const int fh = lane >> 5;           // k-half selector

    v16i acc[4][2] = {};

    auto compute = [&](int rdi) {
        const signed char* cA = lds[rdi][0];
        const signed char* cB = lds[rdi][1];
        #pragma unroll
        for (int s = 0; s < 2; s++) {
            const int cc = s * 2 + fh;                    // 16B chunk index 0..3
            const int ca = (cc ^ ((fr >> 1) & 3)) * 16;   // conflict-free swizzle
            v4i a0 = *(const v4i*)(cA + (wr * 128      + fr) * 64 + ca);
            v4i a1 = *(const v4i*)(cA + (wr * 128 + 32 + fr) * 64 + ca);
            v4i a2 = *(const v4i*)(cA + (wr * 128 + 64 + fr) * 64 + ca);
            v4i a3 = *(const v4i*)(cA + (wr * 128 + 96 + fr) * 64 + ca);
            v4i b0 = *(const v4i*)(cB + (wc * 64       + fr) * 64 + ca);
            v4i b1 = *(const v4i*)(cB + (wc * 64  + 32 + fr) * 64 + ca);
            acc[0][0] = __builtin_amdgcn_mfma_i32_32x32x32_i8(a0, b0, acc[0][0], 0, 0, 0);
            acc[0][1] = __builtin_amdgcn_mfma_i32_32x32x32_i8(a0, b1, acc[0][1], 0, 0, 0);
            acc[1][0] = __builtin_amdgcn_mfma_i32_32x32x32_i8(a1, b0, acc[1][0], 0, 0, 0);
            acc[1][1] = __builtin_amdgcn_mfma_i32_32x32x32_i8(a1, b1, acc[1][1], 0, 0, 0);
            acc[2][0] = __builtin_amdgcn_mfma_i32_32x32x32_i8(a2, b0, acc[2][0], 0, 0, 0);
            acc[2][1] = __builtin_amdgcn_mfma_i32_32x32x32_i8(a2, b1, acc[2][1], 0, 0, 0);
            acc[3][0] = __builtin_amdgcn_mfma_i32_32x32x32_i8(a3, b0, acc[3][0], 0, 0, 0);
            acc[3][1] = __builtin_amdgcn_mfma_i32_32x32x32_i8(a3, b1, acc[3][1], 0, 0, 0);
        }
    };

    // prologue: stage kt=0 -> buf0, kt=1 -> buf1 (8 loads in flight per wave)
    #pragma unroll
    for (int j = 0; j < 4; j++)
        async16(gsrc + (size_t)j * 16 * GK, &lds[0][ldsTensor][ldsSlab + j * 1024]);
    #pragma unroll
    for (int j = 0; j < 4; j++)
        async16(gsrc + (size_t)j * 16 * GK + 64, &lds[1][ldsTensor][ldsSlab + j * 1024]);

    // main loop: wait(own oldest 4 = current buf) -> barrier -> issue kt+2 -> compute kt.
    // Issue is AFTER the barrier, so buf[(kt+2)%3] (== buf[(kt-1)%3]) has been fully
    // read by every wave (their reads happened before they reached this barrier).
    int rd = 0;
    for (int kt = 0; kt < NT - 2; ++kt) {
        asm volatile("s_waitcnt vmcnt(4)" ::: "memory");
        __builtin_amdgcn_s_barrier();
        asm volatile("" ::: "memory");
        int st = rd + 2; if (st >= 3) st -= 3;
        const size_t ko = (size_t)(kt + 2) * 64;
        #pragma unroll
        for (int j = 0; j < 4; j++)
            async16(gsrc + (size_t)j * 16 * GK + ko,
                    &lds[st][ldsTensor][ldsSlab + j * 1024]);
        compute(rd);
        rd = (rd + 1 == 3) ? 0 : rd + 1;
    }
    // kt = NT-2: nothing left to stage; buf NT-1 still in flight (vmcnt 8 -> 4)
    asm volatile("s_waitcnt vmcnt(4)" ::: "memory");
    __builtin_amdgcn_s_barrier();
    asm volatile("" ::: "memory");
    compute(rd);
    rd = (rd + 1 == 3) ? 0 : rd + 1;
    // kt = NT-1: final drain
    asm volatile("s_waitcnt vmcnt(0)" ::: "memory");
    __builtin_amdgcn_s_barrier();
    asm volatile("" ::: "memory");
    compute(rd);

    // epilogue: acc - zw*rowsum_x[m] - zx*rowsum_w[n] + K*zx*zw, scale, +bias
    // 32x32 C/D: col = lane&31, row = (reg&3) + 8*(reg>>2) + 4*(lane>>5)
    const float sxsw = prm[4];
    const int* ip = (const int*)prm;
    const int zxi = ip[5], zwi = ip[6];
    const int kzz = GK * zxi * zwi;
    #pragma unroll
    for (int i = 0; i < 4; i++) {
        #pragma unroll
        for (int j = 0; j < 2; j++) {
            const int col = tn0 + wc * 64 + j * 32 + fr;
            const int ccol = kzz - zxi * rsw[col];
            const float bv = bias[col];
            #pragma unroll
            for (int reg = 0; reg < 16; reg++) {
                const int row = tm0 + wr * 128 + i * 32
                              + (reg & 3) + 8 * (reg >> 2) + 4 * fh;
                const int t = acc[i][j][reg] - zwi * rsx[row] + ccol;
                out[(size_t)row * GN + col] = fmaf(sxsw, (float)t, bv);
            }
        }
    }
}

// ---------- launch ----------
extern "C" void kernel_launch(void* const* d_in, const int* in_sizes, int n_in,
                              void* d_out, int out_size, void* d_ws, size_t ws_size,
                              hipStream_t stream) {
    const float* x    = (const float*)d_in[0];
    const float* Wt   = (const float*)d_in[1];
    const float* bias = (const float*)d_in[2];
    float* out = (float*)d_out;

    char* ws = (char*)d_ws;
    signed char* qx = (signed char*)(ws + QX_OFF);
    signed char* qw = (signed char*)(ws + QW_OFF);
    int* rsx = (int*)(ws + RSX_OFF);
    int* rsw = (int*)(ws + RSW_OFF);
    unsigned* part = (unsigned*)(ws + QX_OFF);   // 24 KB, consumed before qx is written
    float* prm = (float*)(ws + PRM_OFF);

    k_minmax<<<MMB_X + MMB_W, 256, 0, stream>>>((const float4*)x, (const float4*)Wt, part);
    k_params<<<1, 256, 0, stream>>>(part, prm);
    k_quant<<<GM + GN, 256, 0, stream>>>(x, Wt, qx, qw, rsx, rsw, prm);
    k_gemm<<<(GM / 256) * (GN / 256), 512, 0, stream>>>(qx, qw, rsx, rsw, bias,
                                                        prm, out);
}